// Round 5
// baseline (492.016 us; speedup 1.0000x reference)
//
#include <hip/hip_runtime.h>
#include <math.h>

// Problem constants (match reference)
#define N_NODES 50000
#define N_EDGES 800000
#define RELS    3
#define HID     64
#define S_SEEDS 8192
#define OUT_COLS 321   // 1 (pred_missing) + 320 (pred_feat)
#define S_CH    4096   // seed-chunk for the 2048-wide f-branch hidden layer
#define NB      391    // buckets of 128 nodes: ceil(50000/128)
#define BCAP    2560   // per-(rel,bucket) edge capacity (mean 2048, +11 sigma)
#define CHUNK   4096   // edges per bin_fill block
#define NCHUNK  196    // ceil(800000/4096)

// fp16 pipeline (values tiny, no range risk; 10 mantissa bits beats bf16's 7 —
// R6 bf16 failed at 0.023; R8 fp16+CSR passed at 0.0039).
typedef __attribute__((ext_vector_type(8))) _Float16 v8h;  // 8 f16 in 4 VGPRs
typedef __attribute__((ext_vector_type(4))) float v4f;     // MFMA accumulator
typedef __attribute__((ext_vector_type(2))) _Float16 h2;   // packed f16 pair

__device__ __forceinline__ unsigned short f32_to_f16(float f) {
    _Float16 h = (_Float16)f;
    return __builtin_bit_cast(unsigned short, h);
}
__device__ __forceinline__ float f16_to_f32(unsigned short u) {
    return (float)__builtin_bit_cast(_Float16, u);
}
__device__ __forceinline__ h2 u2h2(unsigned u) { return __builtin_bit_cast(h2, u); }
__device__ __forceinline__ unsigned h2u(h2 h) { return __builtin_bit_cast(unsigned, h); }

// ---------------------------------------------------------------------------
// fp16 MFMA GEMM: C = act(A @ Bt^T + bias) [+ noise]
// Tiles: BM x BN. Wave layouts (4 waves / 256 thr):
//   BM=128,BN=128: 2x2 waves of 64x64   (TI=4, TJ=4)
//   BM=128,BN=64 : 4x1 waves of 32x64   (TI=2, TJ=4)
//   BM=64, BN=64 : 2x2 waves of 32x32   (TI=2, TJ=2)  <- occupancy variant
// 3-STAGE pipeline: two register tile-sets (tX/tY, statically named, loop
// unrolled x2) so the global load for tile t+2 is issued at the START of
// step t and consumed (ds_write) at the END of step t+1 -> load latency
// window ~1.5 k-steps (covers L3 ~600-900 cyc), vs one compute phase before.
// XCD-chunked bijective block swizzle (T1/m204): blocks sharing an A-panel
// land on the SAME XCD so the panel is fetched into one L2 once, not 8x.
// ACT: 0=none 1=relu 2=leaky(0.01) 3=tanh.
// ---------------------------------------------------------------------------
template<int ACT, bool OUT_F16, int BN, int BM = 128>
__global__ __launch_bounds__(256) void gemm_mfma_f16(
    const unsigned short* __restrict__ A, long long sAb, int lda,
    const unsigned short* __restrict__ Bt, long long sBb,
    const float* __restrict__ bias, long long sBiasb,
    void* __restrict__ Cv, long long sCb, int ldc,
    const float* __restrict__ noise,
    int M, int Nc, int K)
{
    constexpr int WC = (BN == 128 || BM == 64) ? 2 : 1;  // wave cols
    constexpr int WR = 4 / WC;                           // wave rows
    constexpr int TI = BM / (WR * 16);                   // row frags per wave
    constexpr int TJ = BN / (WC * 16);                   // col frags per wave
    constexpr int TPRA = 256 / BM;                       // threads per A row (2|4)
    constexpr int TPRB = 256 / BN;                       // threads per B row (2|4)

    __shared__ __align__(16) unsigned short As[2][BM][40];
    __shared__ __align__(16) unsigned short Bs[2][BN][40];

    const int r = blockIdx.z;
    A  += (long long)r * sAb;
    Bt += (long long)r * sBb;
    const float* brow = bias ? bias + (long long)r * sBiasb : nullptr;

    // XCD-chunked bijective swizzle over the (x,y) tile plane (per z-slice).
    int bx = blockIdx.x, by = blockIdx.y;
    {
        const int nwg  = gridDim.x * gridDim.y;
        const int orig = by * gridDim.x + bx;
        const int q = nwg >> 3, rm = nwg & 7;
        const int xcd = orig & 7, idx = orig >> 3;
        const int wg = (xcd < rm ? xcd * (q + 1) : rm * (q + 1) + (xcd - rm) * q) + idx;
        bx = wg % gridDim.x;
        by = wg / gridDim.x;
    }

    const int tid  = threadIdx.x;
    const int wave = tid >> 6, lane = tid & 63;
    const int quad = lane >> 4, l16 = lane & 15;
    const int wrow = (wave / WC) * (TI * 16);
    const int wcol = (wave % WC) * (TJ * 16);
    const int row0 = by * BM, col0 = bx * BN;

    v4f acc[TI][TJ] = {};

    const int srow = tid / TPRA;                  // A stage row
    const int ecol = (tid % TPRA) * (32 / TPRA);  // A stage col (f16)
    const int brw  = tid / TPRB;                  // B stage row
    const int bcl  = (tid % TPRB) * (32 / TPRB);  // B stage col (f16)

    const int gr = row0 + srow;
    const bool aval = (gr < M);
    const unsigned short* aptr = A + (long long)gr * lda + ecol;
    const int gn = col0 + brw;
    const bool bval = (gn < Nc);
    const unsigned short* bptr = Bt + (long long)gn * K + bcl;

    struct Tile { int4 a0, a1, b0, b1; };
    auto loadT = [&](Tile& t, int k0) {
        t.a0 = make_int4(0, 0, 0, 0); t.a1 = make_int4(0, 0, 0, 0);
        t.b0 = make_int4(0, 0, 0, 0); t.b1 = make_int4(0, 0, 0, 0);
        if (aval) {
            t.a0 = *(const int4*)(aptr + k0);
            if constexpr (TPRA == 2) t.a1 = *(const int4*)(aptr + k0 + 8);
        }
        if (bval) {
            t.b0 = *(const int4*)(bptr + k0);
            if constexpr (TPRB == 2) t.b1 = *(const int4*)(bptr + k0 + 8);
        }
    };
    auto storeT = [&](const Tile& t, int buf) {
        *(int4*)(&As[buf][srow][ecol]) = t.a0;
        if constexpr (TPRA == 2) *(int4*)(&As[buf][srow][ecol + 8]) = t.a1;
        *(int4*)(&Bs[buf][brw][bcl]) = t.b0;
        if constexpr (TPRB == 2) *(int4*)(&Bs[buf][brw][bcl + 8]) = t.b1;
    };
    auto compute = [&](int buf) {
        v8h af[TI], bfr[TJ];
#pragma unroll
        for (int i = 0; i < TI; i++)
            af[i] = *(const v8h*)(&As[buf][wrow + i * 16 + l16][quad * 8]);
#pragma unroll
        for (int j = 0; j < TJ; j++)
            bfr[j] = *(const v8h*)(&Bs[buf][wcol + j * 16 + l16][quad * 8]);
#pragma unroll
        for (int i = 0; i < TI; i++)
#pragma unroll
            for (int j = 0; j < TJ; j++)
                acc[i][j] = __builtin_amdgcn_mfma_f32_16x16x32_f16(af[i], bfr[j], acc[i][j], 0, 0, 0);
    };

    const int nt = K >> 5;            // K/32 tiles (all K here are mult of 32)

    // ---- prologue: tile 0 -> buf0; tile 1 in flight in tX ----
    Tile tX, tY;
    loadT(tX, 0);
    storeT(tX, 0);
    if (nt > 1) loadT(tX, 32);
    __syncthreads();

    int cur = 0;
    int t = 0;
    // steady pairs: at top of each half-step, issue the 2-ahead load first
    for (; t + 2 < nt; t += 2) {
        loadT(tY, (t + 2) * 32);      // tile t+2: in flight across 1.5 steps
        compute(cur);                 // MFMA tile t
        storeT(tX, cur ^ 1);          // tile t+1 regs -> LDS (vmcnt waits tX only)
        __syncthreads();
        cur ^= 1;
        if (t + 3 < nt) loadT(tX, (t + 3) * 32);
        compute(cur);                 // MFMA tile t+1
        storeT(tY, cur ^ 1);
        __syncthreads();
        cur ^= 1;
    }
    if (t + 1 < nt) {                 // one buffered tile left in tX
        compute(cur);
        storeT(tX, cur ^ 1);
        __syncthreads();
        cur ^= 1;
    }
    compute(cur);                     // last tile

    float* Cf = (float*)Cv + (long long)r * sCb;
    unsigned short* Ch = (unsigned short*)Cv + (long long)r * sCb;
#pragma unroll
    for (int i = 0; i < TI; i++) {
#pragma unroll
        for (int j = 0; j < TJ; j++) {
            int gc = col0 + wcol + j * 16 + l16;
            if (gc >= Nc) continue;
            float bv = brow ? brow[gc] : 0.f;
#pragma unroll
            for (int tt = 0; tt < 4; tt++) {
                int grr = row0 + wrow + i * 16 + quad * 4 + tt;
                if (grr >= M) continue;
                float v = acc[i][j][tt] + bv;
                if (ACT == 1)      v = fmaxf(v, 0.f);
                else if (ACT == 2) v = (v > 0.f) ? v : 0.01f * v;
                else if (ACT == 3) v = tanhf(v);
                if (noise) v += noise[(long long)grr * ldc + gc];
                if (OUT_F16) Ch[(long long)grr * ldc + gc] = f32_to_f16(v);
                else         Cf[(long long)grr * ldc + gc] = v;
            }
        }
    }
}

// ---------------------------------------------------------------------------
// Prep kernels
// ---------------------------------------------------------------------------
__global__ void cvt_f32_f16_kernel(const float* __restrict__ src,
                                   unsigned short* __restrict__ dst, long long n)
{
    long long i = (long long)blockIdx.x * blockDim.x + threadIdx.x;
    if (i < n) dst[i] = f32_to_f16(src[i]);
}

// All 8 weight transposes in ONE launch via descriptor table.
// desc: (R, K, N) f32 -> (R, N, K) f16, 32x32 LDS tiles, coalesced both sides.
struct TD { const float* s; unsigned short* d; int K, N, nbx, nby, b0; };
struct TDs { TD v[8]; };

__global__ __launch_bounds__(256) void transpose_all_kernel(TDs ds)
{
    __shared__ float t[32][33];
    int b = blockIdx.x;
    int k = 0;
#pragma unroll
    for (int q = 1; q < 8; q++) if (b >= ds.v[q].b0) k = q;
    TD td = ds.v[k];
    int local = b - td.b0;
    int per_r = td.nbx * td.nby;
    int r  = local / per_r;
    int rem = local - r * per_r;
    int by = rem / td.nbx, bx = rem - by * td.nbx;

    const float* src = td.s + (long long)r * td.K * td.N;
    unsigned short* dst = td.d + (long long)r * td.K * td.N;
    int n0 = bx * 32, k0 = by * 32;
    int tx = threadIdx.x & 31, ty = threadIdx.x >> 5;   // (32, 8)
#pragma unroll
    for (int i = 0; i < 32; i += 8) {
        int kk = k0 + ty + i, n = n0 + tx;
        if (kk < td.K && n < td.N) t[ty + i][tx] = src[(long long)kk * td.N + n];
    }
    __syncthreads();
#pragma unroll
    for (int i = 0; i < 32; i += 8) {
        int n = n0 + ty + i, kk = k0 + tx;
        if (n < td.N && kk < td.K) dst[(long long)n * td.K + kk] = f32_to_f16(t[tx][ty + i]);
    }
}

// ---------------------------------------------------------------------------
// bin_fill: bin edges by dst>>7 into per-(rel,bucket) runs; block-local sort
// + bulk reservation; all global writes are contiguous runs (coalesced).
// Packed entry: (dst&127)<<16 | src  (src < 50000 < 2^16).
// ---------------------------------------------------------------------------
__global__ __launch_bounds__(256) void bin_fill_kernel(
    const int* __restrict__ s0, const int* __restrict__ d0,
    const int* __restrict__ s1, const int* __restrict__ d1,
    const int* __restrict__ s2, const int* __restrict__ d2,
    int* __restrict__ gcursor,            // (RELS*NB), pre-zeroed
    unsigned int* __restrict__ bedges)    // (RELS*NB, BCAP)
{
    __shared__ int cnt[NB];
    __shared__ int lstart[NB];
    __shared__ int fillc[NB];
    __shared__ int gstart[NB];
    __shared__ int scan[512];
    __shared__ unsigned int svals[CHUNK];
    __shared__ short sbuck[CHUNK];

    const int rel = blockIdx.y;
    const int* sp = (rel == 0) ? s0 : (rel == 1) ? s1 : s2;
    const int* dp = (rel == 0) ? d0 : (rel == 1) ? d1 : d2;
    const int tid = threadIdx.x;
    const int e0 = blockIdx.x * CHUNK;
    const int n  = min(CHUNK, N_EDGES - e0);

    for (int i = tid; i < NB; i += 256) { cnt[i] = 0; fillc[i] = 0; }
    __syncthreads();

    int myb[CHUNK / 256];
    unsigned int myv[CHUNK / 256];
#pragma unroll
    for (int i = 0; i < CHUNK / 256; i++) {
        int off = tid + i * 256;
        if (off < n) {
            int e = e0 + off;
            int s = sp[e], d = dp[e];
            int b = d >> 7;
            myb[i] = b;
            myv[i] = ((unsigned int)(d & 127) << 16) | (unsigned int)s;
            atomicAdd(&cnt[b], 1);
        } else myb[i] = -1;
    }
    __syncthreads();

    scan[tid]       = (tid < NB) ? cnt[tid] : 0;
    scan[tid + 256] = (tid + 256 < NB) ? cnt[tid + 256] : 0;
    __syncthreads();
    for (int off = 1; off < 512; off <<= 1) {
        int a = (tid >= off) ? scan[tid - off] : 0;
        int b = (tid + 256 >= off) ? scan[tid + 256 - off] : 0;
        __syncthreads();
        scan[tid] += a; scan[tid + 256] += b;
        __syncthreads();
    }
    if (tid < NB)       lstart[tid]       = scan[tid] - cnt[tid];
    if (tid + 256 < NB) lstart[tid + 256] = scan[tid + 256] - cnt[tid + 256];
    __syncthreads();

#pragma unroll
    for (int i = 0; i < CHUNK / 256; i++) {
        int b = myb[i];
        if (b >= 0) {
            int p = lstart[b] + atomicAdd(&fillc[b], 1);
            svals[p] = myv[i];
            sbuck[p] = (short)b;
        }
    }
    if (tid < NB && cnt[tid] > 0)
        gstart[tid] = atomicAdd(&gcursor[rel * NB + tid], cnt[tid]);
    if (tid + 256 < NB && cnt[tid + 256] > 0)
        gstart[tid + 256] = atomicAdd(&gcursor[rel * NB + tid + 256], cnt[tid + 256]);
    __syncthreads();

    for (int p = tid; p < n; p += 256) {
        int b = sbuck[p];
        int pos = gstart[b] + (p - lstart[b]);
        bedges[(long long)(rel * NB + b) * BCAP + pos] = svals[p];
    }
}

// ---------------------------------------------------------------------------
// bucket_csr: per (rel,bucket) LDS counting sort -> dst-sorted src list (u16)
// + 128 local row starts.
// ---------------------------------------------------------------------------
__global__ __launch_bounds__(256) void bucket_csr_kernel(
    const unsigned int* __restrict__ bedges,
    const int* __restrict__ gcursor,
    unsigned short* __restrict__ csr16,
    int* __restrict__ browptr)
{
    __shared__ int cnt[128], sc[128], start[128], cur[128];
    __shared__ unsigned short ssorted[BCAP];

    const int id  = blockIdx.y * NB + blockIdx.x;
    const int tid = threadIdx.x;
    const int len = gcursor[id];
    const unsigned int* ep = bedges + (long long)id * BCAP;

    for (int i = tid; i < 128; i += 256) cnt[i] = 0;
    __syncthreads();
    for (int i = tid; i < len; i += 256)
        atomicAdd(&cnt[ep[i] >> 16], 1);
    __syncthreads();

    int v = (tid < 128) ? cnt[tid] : 0;
    if (tid < 128) sc[tid] = v;
    __syncthreads();
    for (int off = 1; off < 128; off <<= 1) {
        int a = (tid < 128 && tid >= off) ? sc[tid - off] : 0;
        __syncthreads();
        if (tid < 128) sc[tid] += a;
        __syncthreads();
    }
    if (tid < 128) { start[tid] = sc[tid] - v; cur[tid] = sc[tid] - v; }
    __syncthreads();

    for (int i = tid; i < len; i += 256) {
        unsigned int vv = ep[i];
        int dl = vv >> 16;
        int pos = atomicAdd(&cur[dl], 1);
        ssorted[pos] = (unsigned short)(vv & 0xFFFFu);
    }
    __syncthreads();

    for (int i = tid; i < len; i += 256)
        csr16[(long long)id * BCAP + i] = ssorted[i];
    if (tid < 128) browptr[id * 128 + tid] = start[tid];
}

// ---------------------------------------------------------------------------
// gather_csr_f16: ONE WAVE PER NODE, all 3 relations sequentially (pointer
// loads for all rels hoisted up front; 3x fewer waves; prologue amortized).
// 4x16 lane split: group g handles edges i = p0+g, p0+g+4, ...; lane l16
// loads uint2 (4 f16 = 8 B) of the source row -> one VMEM instr fetches 4
// FULL rows (512 B). Accumulation in PACKED f16 (v_pk_add_f16): 2 ops per
// uint2 instead of 8 (4x VALU cut); partial sums <= ~|30| so f16-safe.
// Cross-group combine: 2 rounds of __shfl_xor on packed regs.
// ---------------------------------------------------------------------------
__global__ __launch_bounds__(256) void gather_csr_f16_kernel(
    const unsigned short* __restrict__ feat,
    const unsigned short* __restrict__ csr16,
    const int* __restrict__ browptr,
    const int* __restrict__ gcursor,
    unsigned short* __restrict__ agg,
    int M)
{
    int d = (blockIdx.x * 256 + threadIdx.x) >> 6;   // node
    int lane = threadIdx.x & 63;
    if (d >= M) return;
    int bucket = d >> 7, dl = d & 127;
    const int g = lane >> 4;                           // edge group 0..3
    const unsigned fo = (unsigned)((lane & 15) << 2);  // feature quad offset

    // hoisted row pointers for all 3 rels (6 independent loads in flight)
    int p0[RELS], p1[RELS];
#pragma unroll
    for (int r = 0; r < RELS; r++) {
        int id = r * NB + bucket;
        p0[r] = browptr[id * 128 + dl];
        p1[r] = (dl == 127) ? gcursor[id] : browptr[id * 128 + dl + 1];
    }

    unsigned short* outp = agg + (long long)d * (RELS * HID);

#pragma unroll
    for (int r = 0; r < RELS; r++) {
        const unsigned short* cp = csr16 + (long long)(r * NB + bucket) * BCAP;
        h2 aA01 = (h2)0, aA23 = (h2)0, aB01 = (h2)0, aB23 = (h2)0;
        const int e1 = p1[r];
        int i = p0[r] + g;
        for (; i + 12 < e1; i += 16) {   // 16 edges/wave per iter (4/group)
            unsigned s0 = cp[i], s1 = cp[i + 4], s2 = cp[i + 8], s3 = cp[i + 12];
            uint2 w0 = *(const uint2*)(feat + (s0 << 6) + fo);
            uint2 w1 = *(const uint2*)(feat + (s1 << 6) + fo);
            uint2 w2 = *(const uint2*)(feat + (s2 << 6) + fo);
            uint2 w3 = *(const uint2*)(feat + (s3 << 6) + fo);
            aA01 += u2h2(w0.x) + u2h2(w1.x);
            aA23 += u2h2(w0.y) + u2h2(w1.y);
            aB01 += u2h2(w2.x) + u2h2(w3.x);
            aB23 += u2h2(w2.y) + u2h2(w3.y);
        }
        if (i + 4 < e1) {                // 2 more edges for this group
            unsigned s0 = cp[i], s1 = cp[i + 4];
            uint2 w0 = *(const uint2*)(feat + (s0 << 6) + fo);
            uint2 w1 = *(const uint2*)(feat + (s1 << 6) + fo);
            aA01 += u2h2(w0.x) + u2h2(w1.x);
            aA23 += u2h2(w0.y) + u2h2(w1.y);
            i += 8;
        }
        if (i < e1) {                    // last edge for this group
            unsigned s0 = cp[i];
            uint2 w0 = *(const uint2*)(feat + (s0 << 6) + fo);
            aB01 += u2h2(w0.x);
            aB23 += u2h2(w0.y);
        }
        h2 a01 = aA01 + aB01, a23 = aA23 + aB23;

        // combine the 4 edge groups (packed): lanes l, l+16, l+32, l+48
        a01 += u2h2((unsigned)__shfl_xor((int)h2u(a01), 16));
        a23 += u2h2((unsigned)__shfl_xor((int)h2u(a23), 16));
        a01 += u2h2((unsigned)__shfl_xor((int)h2u(a01), 32));
        a23 += u2h2((unsigned)__shfl_xor((int)h2u(a23), 32));

        if (lane < 16) {
            float inv = 1.0f / fmaxf((float)(e1 - p0[r]), 1.0f);
            ushort4 o;
            o.x = f32_to_f16((float)a01.x * inv);
            o.y = f32_to_f16((float)a01.y * inv);
            o.z = f32_to_f16((float)a23.x * inv);
            o.w = f32_to_f16((float)a23.y * inv);
            *(ushort4*)(outp + r * HID + fo) = o;
        }
    }
}

// ---------------------------------------------------------------------------
// d-branch final head: out[r,s,0] = relu(z2d[r,s,:] . dW3[r] + db3[r])
// ---------------------------------------------------------------------------
__global__ void dhead_kernel(const float* __restrict__ z2d,
                             const float* __restrict__ dW3,
                             const float* __restrict__ db3,
                             float* __restrict__ out)
{
    int idx = blockIdx.x * blockDim.x + threadIdx.x;
    if (idx >= RELS * S_SEEDS) return;
    int r = idx / S_SEEDS;
    const float* zp = z2d + (long long)idx * 32;
    const float* wp = dW3 + r * 32;
    float acc = db3[r];
#pragma unroll
    for (int k = 0; k < 32; k++) acc += zp[k] * wp[k];
    out[(long long)idx * OUT_COLS] = fmaxf(acc, 0.f);
}

// ---------------------------------------------------------------------------
extern "C" void kernel_launch(void* const* d_in, const int* in_sizes, int n_in,
                              void* d_out, int out_size, void* d_ws, size_t ws_size,
                              hipStream_t stream)
{
    const float* x     = (const float*)d_in[0];
    const float* noise = (const float*)d_in[1];
    // d_in[2] = seeds: only its shape matters (S=8192); unused.
    const int* srcs[RELS] = { (const int*)d_in[3], (const int*)d_in[5], (const int*)d_in[7] };
    const int* dsts[RELS] = { (const int*)d_in[4], (const int*)d_in[6], (const int*)d_in[8] };
    const float* Wc1  = (const float*)d_in[9];
    const float* bc1  = (const float*)d_in[10];
    const float* Wc2  = (const float*)d_in[11];
    const float* bc2  = (const float*)d_in[12];
    const float* Wlin = (const float*)d_in[13];
    const float* blin = (const float*)d_in[14];
    const float* dW1  = (const float*)d_in[15];
    const float* db1  = (const float*)d_in[16];
    const float* dW2  = (const float*)d_in[17];
    const float* db2  = (const float*)d_in[18];
    const float* dW3  = (const float*)d_in[19];
    const float* db3  = (const float*)d_in[20];
    const float* fW1  = (const float*)d_in[21];
    const float* fb1  = (const float*)d_in[22];
    const float* fW2  = (const float*)d_in[23];
    const float* fb2  = (const float*)d_in[24];
    const float* fW3  = (const float*)d_in[25];
    const float* fb3  = (const float*)d_in[26];
    float* out = (float*)d_out;
    float* w   = (float*)d_ws;

    // ---- workspace layout (4-byte units; ~88.5 MB peak, all 16B-aligned) ----
    int* gcursor = (int*)w;                                     // 1,280
    int* browptr = (int*)(w + 1280);                            // 150,144
    unsigned short* csr16 = (unsigned short*)(w + 151424);      // 1,501,440 f
    unsigned short* aggx_hf = (unsigned short*)(w + 1652864);   // REGION_A
    unsigned int*   bedges  = (unsigned int*)(w + 1652864 + 2400000);
    float*          z2d     = w + 1652864 + 2400000;
    unsigned short* z2hf    = (unsigned short*)(w + 1652864);
    unsigned short* xhf  = (unsigned short*)(w + 14235776);     // REGION_B
    unsigned short* z1hf = (unsigned short*)(w + 14235776);
    unsigned short* h1hf   = (unsigned short*)(w + 17381504);
    unsigned short* agg2hf = (unsigned short*)(w + 18981504);
    unsigned short* h2shf  = (unsigned short*)(w + 19767936);
    unsigned short* hshf   = (unsigned short*)(w + 20030080);
    unsigned short* WcT1   = (unsigned short*)(w + 20292224);
    unsigned short* WcT2   = (unsigned short*)(w + 20298368);
    unsigned short* WlinT  = (unsigned short*)(w + 20304512);
    unsigned short* dW1ht  = (unsigned short*)(w + 20306560);
    unsigned short* dW2ht  = (unsigned short*)(w + 20331136);
    unsigned short* fW1ht  = (unsigned short*)(w + 20343424);
    unsigned short* fW2ht  = (unsigned short*)(w + 20368000);
    unsigned short* fW3ht  = (unsigned short*)(w + 21154432);

    // ---- edge binning + per-bucket CSR ----
    hipMemsetAsync(gcursor, 0, (size_t)RELS * NB * sizeof(int), stream);
    bin_fill_kernel<<<dim3(NCHUNK, RELS), 256, 0, stream>>>(
        srcs[0], dsts[0], srcs[1], dsts[1], srcs[2], dsts[2], gcursor, bedges);
    bucket_csr_kernel<<<dim3(NB, RELS), 256, 0, stream>>>(
        bedges, gcursor, csr16, browptr);

    // ---- prep: x -> f16; all 8 weight transposes in one launch ----
    cvt_f32_f16_kernel<<<(N_NODES * HID + 255) / 256, 256, 0, stream>>>(x, xhf, (long long)N_NODES * HID);
    {
        TDs ds;
        int b0 = 0;
        auto add = [&](int k, const float* s, unsigned short* d, int K, int N, int rels) {
            ds.v[k].s = s; ds.v[k].d = d; ds.v[k].K = K; ds.v[k].N = N;
            ds.v[k].nbx = (N + 31) / 32; ds.v[k].nby = (K + 31) / 32; ds.v[k].b0 = b0;
            b0 += ds.v[k].nbx * ds.v[k].nby * rels;
        };
        add(0, Wc1, WcT1, 192, 64, 1);
        add(1, Wc2, WcT2, 192, 64, 1);
        add(2, Wlin, WlinT, 64, 64, 1);
        add(3, dW1, dW1ht, 64, 256, RELS);
        add(4, dW2, dW2ht, 256, 32, RELS);
        add(5, fW1, fW1ht, 64, 256, RELS);
        add(6, fW2, fW2ht, 256, 2048, RELS);
        add(7, fW3, fW3ht, 2048, 320, RELS);
        transpose_all_kernel<<<b0, 256, 0, stream>>>(ds);
    }

    // ---- conv layer 1: CSR gather x -> aggx (50000x192), MFMA -> h1hf ----
    gather_csr_f16_kernel<<<(N_NODES + 3) / 4, 256, 0, stream>>>(
        xhf, csr16, browptr, gcursor, aggx_hf, N_NODES);
    gemm_mfma_f16<1, true, 64, 64><<<dim3(1, (N_NODES + 63) / 64, 1), 256, 0, stream>>>(
        aggx_hf, 0, RELS * HID, WcT1, 0, bc1, 0,
        h1hf, 0, HID, nullptr, N_NODES, HID, RELS * HID);

    // ---- conv layer 2 (rows < S only), MFMA -> h2shf ----
    gather_csr_f16_kernel<<<(S_SEEDS + 3) / 4, 256, 0, stream>>>(
        h1hf, csr16, browptr, gcursor, agg2hf, S_SEEDS);
    gemm_mfma_f16<1, true, 64, 64><<<dim3(1, S_SEEDS / 64, 1), 256, 0, stream>>>(
        agg2hf, 0, RELS * HID, WcT2, 0, bc2, 0,
        h2shf, 0, HID, nullptr, S_SEEDS, HID, RELS * HID);

    // ---- hs = leaky(h2s @ Wlin + blin) + noise[:S] ----
    gemm_mfma_f16<2, true, 64, 64><<<dim3(1, S_SEEDS / 64, 1), 256, 0, stream>>>(
        h2shf, 0, HID, WlinT, 0, blin, 0,
        hshf, 0, HID, noise, S_SEEDS, HID, HID);

    // ---- d-branch: z1 -> z2d -> dhead ----
    gemm_mfma_f16<2, true, 128><<<dim3(2, S_SEEDS / 128, RELS), 256, 0, stream>>>(
        hshf, 0, HID, dW1ht, 256LL * 64, db1, 256,
        z1hf, (long long)S_SEEDS * 256, 256, nullptr, S_SEEDS, 256, HID);
    gemm_mfma_f16<2, false, 64, 64><<<dim3(1, S_SEEDS / 64, RELS), 256, 0, stream>>>(
        z1hf, (long long)S_SEEDS * 256, 256, dW2ht, 32LL * 256, db2, 32,
        z2d, (long long)S_SEEDS * 32, 32, nullptr, S_SEEDS, 32, 256);
    dhead_kernel<<<(RELS * S_SEEDS + 255) / 256, 256, 0, stream>>>(z2d, dW3, db3, out);

    // ---- f-branch: z1 -> chunked (fW2, fW3) ----
    gemm_mfma_f16<1, true, 128><<<dim3(2, S_SEEDS / 128, RELS), 256, 0, stream>>>(
        hshf, 0, HID, fW1ht, 256LL * 64, fb1, 256,
        z1hf, (long long)S_SEEDS * 256, 256, nullptr, S_SEEDS, 256, HID);
    for (int c = 0; c < S_SEEDS / S_CH; c++) {
        long long s0 = (long long)c * S_CH;
        gemm_mfma_f16<1, true, 128><<<dim3(2048 / 128, S_CH / 128, RELS), 256, 0, stream>>>(
            z1hf + s0 * 256, (long long)S_SEEDS * 256, 256,
            fW2ht, 2048LL * 256, fb2, 2048,
            z2hf, (long long)S_CH * 2048, 2048, nullptr, S_CH, 2048, 256);
        gemm_mfma_f16<3, false, 64, 64><<<dim3(5, S_CH / 64, RELS), 256, 0, stream>>>(
            z2hf, (long long)S_CH * 2048, 2048,
            fW3ht, 320LL * 2048, fb3, 320,
            out + s0 * OUT_COLS + 1, (long long)S_SEEDS * OUT_COLS, OUT_COLS,
            nullptr, S_CH, 320, 2048);
    }
}

// Round 6
// 459.781 us; speedup vs baseline: 1.0701x; 1.0701x over previous
//
#include <hip/hip_runtime.h>
#include <math.h>

// Problem constants (match reference)
#define N_NODES 50000
#define N_EDGES 800000
#define RELS    3
#define HID     64
#define S_SEEDS 8192
#define OUT_COLS 321   // 1 (pred_missing) + 320 (pred_feat)
#define NB      391    // buckets of 128 nodes: ceil(50000/128)
#define BCAP    2560   // per-(rel,bucket) edge capacity (mean 2048, +11 sigma)
#define CHUNK   4096   // edges per bin_fill block
#define NCHUNK  196    // ceil(800000/4096)

// fp16 pipeline (values tiny, no range risk; 10 mantissa bits beats bf16's 7 —
// R6 bf16 failed at 0.023; R8 fp16+CSR passed at 0.0039).
typedef __attribute__((ext_vector_type(8))) _Float16 v8h;  // 8 f16 in 4 VGPRs
typedef __attribute__((ext_vector_type(4))) float v4f;     // MFMA accumulator
typedef __attribute__((ext_vector_type(2))) _Float16 h2;   // packed f16 pair

__device__ __forceinline__ unsigned short f32_to_f16(float f) {
    _Float16 h = (_Float16)f;
    return __builtin_bit_cast(unsigned short, h);
}
__device__ __forceinline__ float f16_to_f32(unsigned short u) {
    return (float)__builtin_bit_cast(_Float16, u);
}
__device__ __forceinline__ h2 u2h2(unsigned u) { return __builtin_bit_cast(h2, u); }
__device__ __forceinline__ unsigned h2u(h2 h) { return __builtin_bit_cast(unsigned, h); }

// ---------------------------------------------------------------------------
// fp16 MFMA GEMM: C = act(A @ Bt^T + bias) [+ noise]
// Tiles: BM x BN, 3-stage reg-prefetch pipeline, XCD-chunked block swizzle.
// ACT: 0=none 1=relu 2=leaky(0.01) 3=tanh.   (used for conv/lin/d-branch/fW1)
// ---------------------------------------------------------------------------
template<int ACT, bool OUT_F16, int BN, int BM = 128>
__global__ __launch_bounds__(256) void gemm_mfma_f16(
    const unsigned short* __restrict__ A, long long sAb, int lda,
    const unsigned short* __restrict__ Bt, long long sBb,
    const float* __restrict__ bias, long long sBiasb,
    void* __restrict__ Cv, long long sCb, int ldc,
    const float* __restrict__ noise,
    int M, int Nc, int K)
{
    constexpr int WC = (BN == 128 || BM == 64) ? 2 : 1;  // wave cols
    constexpr int WR = 4 / WC;                           // wave rows
    constexpr int TI = BM / (WR * 16);                   // row frags per wave
    constexpr int TJ = BN / (WC * 16);                   // col frags per wave
    constexpr int TPRA = 256 / BM;                       // threads per A row (2|4)
    constexpr int TPRB = 256 / BN;                       // threads per B row (2|4)

    __shared__ __align__(16) unsigned short As[2][BM][40];
    __shared__ __align__(16) unsigned short Bs[2][BN][40];

    const int r = blockIdx.z;
    A  += (long long)r * sAb;
    Bt += (long long)r * sBb;
    const float* brow = bias ? bias + (long long)r * sBiasb : nullptr;

    // XCD-chunked bijective swizzle over the (x,y) tile plane (per z-slice).
    int bx = blockIdx.x, by = blockIdx.y;
    {
        const int nwg  = gridDim.x * gridDim.y;
        const int orig = by * gridDim.x + bx;
        const int q = nwg >> 3, rm = nwg & 7;
        const int xcd = orig & 7, idx = orig >> 3;
        const int wg = (xcd < rm ? xcd * (q + 1) : rm * (q + 1) + (xcd - rm) * q) + idx;
        bx = wg % gridDim.x;
        by = wg / gridDim.x;
    }

    const int tid  = threadIdx.x;
    const int wave = tid >> 6, lane = tid & 63;
    const int quad = lane >> 4, l16 = lane & 15;
    const int wrow = (wave / WC) * (TI * 16);
    const int wcol = (wave % WC) * (TJ * 16);
    const int row0 = by * BM, col0 = bx * BN;

    v4f acc[TI][TJ] = {};

    const int srow = tid / TPRA;                  // A stage row
    const int ecol = (tid % TPRA) * (32 / TPRA);  // A stage col (f16)
    const int brw  = tid / TPRB;                  // B stage row
    const int bcl  = (tid % TPRB) * (32 / TPRB);  // B stage col (f16)

    const int gr = row0 + srow;
    const bool aval = (gr < M);
    const unsigned short* aptr = A + (long long)gr * lda + ecol;
    const int gn = col0 + brw;
    const bool bval = (gn < Nc);
    const unsigned short* bptr = Bt + (long long)gn * K + bcl;

    struct Tile { int4 a0, a1, b0, b1; };
    auto loadT = [&](Tile& t, int k0) {
        t.a0 = make_int4(0, 0, 0, 0); t.a1 = make_int4(0, 0, 0, 0);
        t.b0 = make_int4(0, 0, 0, 0); t.b1 = make_int4(0, 0, 0, 0);
        if (aval) {
            t.a0 = *(const int4*)(aptr + k0);
            if constexpr (TPRA == 2) t.a1 = *(const int4*)(aptr + k0 + 8);
        }
        if (bval) {
            t.b0 = *(const int4*)(bptr + k0);
            if constexpr (TPRB == 2) t.b1 = *(const int4*)(bptr + k0 + 8);
        }
    };
    auto storeT = [&](const Tile& t, int buf) {
        *(int4*)(&As[buf][srow][ecol]) = t.a0;
        if constexpr (TPRA == 2) *(int4*)(&As[buf][srow][ecol + 8]) = t.a1;
        *(int4*)(&Bs[buf][brw][bcl]) = t.b0;
        if constexpr (TPRB == 2) *(int4*)(&Bs[buf][brw][bcl + 8]) = t.b1;
    };
    auto compute = [&](int buf) {
        v8h af[TI], bfr[TJ];
#pragma unroll
        for (int i = 0; i < TI; i++)
            af[i] = *(const v8h*)(&As[buf][wrow + i * 16 + l16][quad * 8]);
#pragma unroll
        for (int j = 0; j < TJ; j++)
            bfr[j] = *(const v8h*)(&Bs[buf][wcol + j * 16 + l16][quad * 8]);
#pragma unroll
        for (int i = 0; i < TI; i++)
#pragma unroll
            for (int j = 0; j < TJ; j++)
                acc[i][j] = __builtin_amdgcn_mfma_f32_16x16x32_f16(af[i], bfr[j], acc[i][j], 0, 0, 0);
    };

    const int nt = K >> 5;            // K/32 tiles (all K here are mult of 32)

    // ---- prologue: tile 0 -> buf0; tile 1 in flight in tX ----
    Tile tX, tY;
    loadT(tX, 0);
    storeT(tX, 0);
    if (nt > 1) loadT(tX, 32);
    __syncthreads();

    int cur = 0;
    int t = 0;
    for (; t + 2 < nt; t += 2) {
        loadT(tY, (t + 2) * 32);      // tile t+2: in flight across 1.5 steps
        compute(cur);                 // MFMA tile t
        storeT(tX, cur ^ 1);          // tile t+1 regs -> LDS
        __syncthreads();
        cur ^= 1;
        if (t + 3 < nt) loadT(tX, (t + 3) * 32);
        compute(cur);                 // MFMA tile t+1
        storeT(tY, cur ^ 1);
        __syncthreads();
        cur ^= 1;
    }
    if (t + 1 < nt) {                 // one buffered tile left in tX
        compute(cur);
        storeT(tX, cur ^ 1);
        __syncthreads();
        cur ^= 1;
    }
    compute(cur);                     // last tile

    float* Cf = (float*)Cv + (long long)r * sCb;
    unsigned short* Ch = (unsigned short*)Cv + (long long)r * sCb;
#pragma unroll
    for (int i = 0; i < TI; i++) {
#pragma unroll
        for (int j = 0; j < TJ; j++) {
            int gc = col0 + wcol + j * 16 + l16;
            if (gc >= Nc) continue;
            float bv = brow ? brow[gc] : 0.f;
#pragma unroll
            for (int tt = 0; tt < 4; tt++) {
                int grr = row0 + wrow + i * 16 + quad * 4 + tt;
                if (grr >= M) continue;
                float v = acc[i][j][tt] + bv;
                if (ACT == 1)      v = fmaxf(v, 0.f);
                else if (ACT == 2) v = (v > 0.f) ? v : 0.01f * v;
                else if (ACT == 3) v = tanhf(v);
                if (noise) v += noise[(long long)grr * ldc + gc];
                if (OUT_F16) Ch[(long long)grr * ldc + gc] = f32_to_f16(v);
                else         Cf[(long long)grr * ldc + gc] = v;
            }
        }
    }
}

// ---------------------------------------------------------------------------
// fused_f23: pred_feat = tanh( relu(z1 @ fW2 + fb2) @ fW3 + fb3 )
// One block (512 thr, 8 waves) = 128 seeds x 1 rel. z1[128][256] held in
// REGISTERS (zfr, 64 VGPR/wave). Loop h0 over 2048 in 64-chunks:
//   stage fW2[h0:h0+64][256] (32KB) + fW3t[:,h0:h0+64] (40KB) into
//   XOR-swizzled LDS (byte ^= (row&7)<<4 within 128B-granule space; write
//   and read sides swizzled identically — 2-way max bank aliasing);
//   phase A: z2c[128][64] = relu(z1@fW2c + fb2) -> f16 in swizzled LDS
//            (wave = 32 rows x 32 cols; 32 MFMA);
//   phase B: acc3[128][320] += z2c @ fW3c (wave = 32 rows x 160 cols;
//            TI=2 x TJ=10 x 2 ksteps = 40 MFMA; acc3 persists, 80 VGPR).
//   Next chunk's weights global->reg issued during phase A epilogue (T14).
// z2 NEVER goes to global: kills the 200MB z2hf round trip + fW3's
// latency-exposed K=2048 global loop. All dims exact -> no bounds checks.
// ---------------------------------------------------------------------------
__global__ __launch_bounds__(512) void fused_f23_kernel(
    const unsigned short* __restrict__ z1,     // (R, S, 256) f16
    const unsigned short* __restrict__ fW2t,   // (R, 2048, 256) f16
    const float* __restrict__ fb2,             // (R, 2048)
    const unsigned short* __restrict__ fW3t,   // (R, 320, 2048) f16
    const float* __restrict__ fb3,             // (R, 320)
    float* __restrict__ out)                   // (R, S, 321), cols 1..320
{
    __shared__ __align__(16) unsigned short Bs2[64 * 256];   // 32 KB, swizzled
    __shared__ __align__(16) unsigned short Bs3[320 * 64];   // 40 KB, swizzled
    __shared__ __align__(16) unsigned short Z2[128 * 64];    // 16 KB, swizzled
    __shared__ float Fb2[2048];                              // 8 KB

    // XCD-chunked swizzle over linear block id (192 % 8 == 0)
    int orig = blockIdx.y * gridDim.x + blockIdx.x;
    {
        const int q = (gridDim.x * gridDim.y) >> 3;
        orig = (orig & 7) * q + (orig >> 3);
    }
    const int rel = orig / gridDim.x;
    const int s0  = (orig % gridDim.x) * 128;

    const int tid = threadIdx.x;           // 0..511
    const int wave = tid >> 6;             // 0..7
    const int lane = tid & 63;
    const int quad = lane >> 4, l16 = lane & 15;
    const int wr = wave >> 1;              // row group (4 x 32 rows)
    const int wc = wave & 1;               // col group

    const unsigned short* z1p = z1 + ((long long)rel * S_SEEDS + s0) * 256;
    const unsigned short* w2p = fW2t + (long long)rel * 2048 * 256;
    const unsigned short* w3p = fW3t + (long long)rel * 320 * 2048;

    // ---- fb2 -> LDS (once) ----
    for (int u = tid; u < 2048; u += 512) Fb2[u] = fb2[rel * 2048 + u];

    // ---- z1 A-fragments -> registers: rows wr*32 + i*16 + l16, all K=256 ----
    v8h zfr[2][8];
#pragma unroll
    for (int i = 0; i < 2; i++) {
        const unsigned short* rp = z1p + (wr * 32 + i * 16 + l16) * 256 + quad * 8;
#pragma unroll
        for (int ks = 0; ks < 8; ks++)
            zfr[i][ks] = *(const v8h*)(rp + ks * 32);
    }

    // ---- chunk staging (global->reg, reg->swizzled LDS) ----
    int4 sr2[4], sr3[5];
    auto stageLoad = [&](int h0) {
#pragma unroll
        for (int u = 0; u < 4; u++) {              // fW2: 2048 granules of 16B
            int g = tid + u * 512;
            int row = g >> 5, gc = g & 31;
            sr2[u] = *(const int4*)(w2p + (h0 + row) * 256 + gc * 8);
        }
#pragma unroll
        for (int u = 0; u < 5; u++) {              // fW3: 2560 granules
            int g = tid + u * 512;
            int n = g >> 3, gc = g & 7;
            sr3[u] = *(const int4*)(w3p + (long long)n * 2048 + h0 + gc * 8);
        }
    };
    auto stageWrite = [&]() {
        char* b2 = (char*)Bs2; char* b3 = (char*)Bs3;
#pragma unroll
        for (int u = 0; u < 4; u++) {
            int g = tid + u * 512;
            int row = g >> 5, gc = g & 31;
            *(int4*)(b2 + row * 512 + ((gc * 16) ^ ((row & 7) << 4))) = sr2[u];
        }
#pragma unroll
        for (int u = 0; u < 5; u++) {
            int g = tid + u * 512;
            int n = g >> 3, gc = g & 7;
            *(int4*)(b3 + n * 128 + ((gc * 16) ^ ((n & 7) << 4))) = sr3[u];
        }
    };

    v4f acc3[2][10] = {};

    stageLoad(0);
    stageWrite();
    __syncthreads();

    for (int c = 0; c < 32; c++) {
        const int h0 = c * 64;
        // ---- phase A: z2c = relu(z1 @ fW2c + fb2); wave tile 32x32 ----
        v4f a2[2][2] = {};
        const char* cb2 = (const char*)Bs2;
#pragma unroll
        for (int ks = 0; ks < 8; ks++) {
            v8h bf[2];
#pragma unroll
            for (int j = 0; j < 2; j++) {
                int hl = wc * 32 + j * 16 + l16;
                bf[j] = *(const v8h*)(cb2 + hl * 512 +
                        ((ks * 64 + quad * 16) ^ ((hl & 7) << 4)));
            }
#pragma unroll
            for (int i = 0; i < 2; i++)
#pragma unroll
                for (int j = 0; j < 2; j++)
                    a2[i][j] = __builtin_amdgcn_mfma_f32_16x16x32_f16(zfr[i][ks], bf[j], a2[i][j], 0, 0, 0);
        }
        if (c + 1 < 32) stageLoad(h0 + 64);   // next weights: hide under B
        // bias + relu + cvt -> Z2 (swizzled)
        char* zb = (char*)Z2;
#pragma unroll
        for (int i = 0; i < 2; i++)
#pragma unroll
            for (int j = 0; j < 2; j++) {
                int col = wc * 32 + j * 16 + l16;
                float bv = Fb2[h0 + col];
#pragma unroll
                for (int t = 0; t < 4; t++) {
                    int row = wr * 32 + i * 16 + quad * 4 + t;
                    float v = fmaxf(a2[i][j][t] + bv, 0.f);
                    *(unsigned short*)(zb + row * 128 +
                        ((col * 2) ^ ((row & 7) << 4))) = f32_to_f16(v);
                }
            }
        __syncthreads();
        // ---- phase B: acc3 += Z2 @ fW3c; wave tile 32 rows x 160 cols ----
#pragma unroll
        for (int ks = 0; ks < 2; ks++) {
            v8h af[2], bf3[10];
#pragma unroll
            for (int i = 0; i < 2; i++) {
                int row = wr * 32 + i * 16 + l16;
                af[i] = *(const v8h*)((const char*)Z2 + row * 128 +
                        ((ks * 64 + quad * 16) ^ ((row & 7) << 4)));
            }
#pragma unroll
            for (int j = 0; j < 10; j++) {
                int n = wc * 160 + j * 16 + l16;
                bf3[j] = *(const v8h*)((const char*)Bs3 + n * 128 +
                        ((ks * 64 + quad * 16) ^ ((n & 7) << 4)));
            }
#pragma unroll
            for (int i = 0; i < 2; i++)
#pragma unroll
                for (int j = 0; j < 10; j++)
                    acc3[i][j] = __builtin_amdgcn_mfma_f32_16x16x32_f16(af[i], bf3[j], acc3[i][j], 0, 0, 0);
        }
        __syncthreads();
        if (c + 1 < 32) {                     // land next chunk's weights
            stageWrite();
            __syncthreads();
        }
    }

    // ---- epilogue: tanh(acc3 + fb3) -> out[:, 1:321] ----
    const float* fb3p = fb3 + rel * 320;
    float* op = out + ((long long)(rel * S_SEEDS + s0)) * OUT_COLS + 1;
#pragma unroll
    for (int i = 0; i < 2; i++)
#pragma unroll
        for (int j = 0; j < 10; j++) {
            int col = wc * 160 + j * 16 + l16;
            float bv = fb3p[col];
#pragma unroll
            for (int t = 0; t < 4; t++) {
                int row = wr * 32 + i * 16 + quad * 4 + t;
                op[(long long)row * OUT_COLS + col] = tanhf(acc3[i][j][t] + bv);
            }
        }
}

// ---------------------------------------------------------------------------
// Prep kernels
// ---------------------------------------------------------------------------
__global__ void cvt_f32_f16_kernel(const float* __restrict__ src,
                                   unsigned short* __restrict__ dst, long long n)
{
    long long i = (long long)blockIdx.x * blockDim.x + threadIdx.x;
    if (i < n) dst[i] = f32_to_f16(src[i]);
}

// All 8 weight transposes in ONE launch via descriptor table.
// desc: (R, K, N) f32 -> (R, N, K) f16, 32x32 LDS tiles, coalesced both sides.
struct TD { const float* s; unsigned short* d; int K, N, nbx, nby, b0; };
struct TDs { TD v[8]; };

__global__ __launch_bounds__(256) void transpose_all_kernel(TDs ds)
{
    __shared__ float t[32][33];
    int b = blockIdx.x;
    int k = 0;
#pragma unroll
    for (int q = 1; q < 8; q++) if (b >= ds.v[q].b0) k = q;
    TD td = ds.v[k];
    int local = b - td.b0;
    int per_r = td.nbx * td.nby;
    int r  = local / per_r;
    int rem = local - r * per_r;
    int by = rem / td.nbx, bx = rem - by * td.nbx;

    const float* src = td.s + (long long)r * td.K * td.N;
    unsigned short* dst = td.d + (long long)r * td.K * td.N;
    int n0 = bx * 32, k0 = by * 32;
    int tx = threadIdx.x & 31, ty = threadIdx.x >> 5;   // (32, 8)
#pragma unroll
    for (int i = 0; i < 32; i += 8) {
        int kk = k0 + ty + i, n = n0 + tx;
        if (kk < td.K && n < td.N) t[ty + i][tx] = src[(long long)kk * td.N + n];
    }
    __syncthreads();
#pragma unroll
    for (int i = 0; i < 32; i += 8) {
        int n = n0 + ty + i, kk = k0 + tx;
        if (n < td.N && kk < td.K) dst[(long long)n * td.K + kk] = f32_to_f16(t[tx][ty + i]);
    }
}

// ---------------------------------------------------------------------------
// bin_fill: bin edges by dst>>7 into per-(rel,bucket) runs; block-local sort
// + bulk reservation; all global writes are contiguous runs (coalesced).
// Packed entry: (dst&127)<<16 | src  (src < 50000 < 2^16).
// ---------------------------------------------------------------------------
__global__ __launch_bounds__(256) void bin_fill_kernel(
    const int* __restrict__ s0, const int* __restrict__ d0,
    const int* __restrict__ s1, const int* __restrict__ d1,
    const int* __restrict__ s2, const int* __restrict__ d2,
    int* __restrict__ gcursor,            // (RELS*NB), pre-zeroed
    unsigned int* __restrict__ bedges)    // (RELS*NB, BCAP)
{
    __shared__ int cnt[NB];
    __shared__ int lstart[NB];
    __shared__ int fillc[NB];
    __shared__ int gstart[NB];
    __shared__ int scan[512];
    __shared__ unsigned int svals[CHUNK];
    __shared__ short sbuck[CHUNK];

    const int rel = blockIdx.y;
    const int* sp = (rel == 0) ? s0 : (rel == 1) ? s1 : s2;
    const int* dp = (rel == 0) ? d0 : (rel == 1) ? d1 : d2;
    const int tid = threadIdx.x;
    const int e0 = blockIdx.x * CHUNK;
    const int n  = min(CHUNK, N_EDGES - e0);

    for (int i = tid; i < NB; i += 256) { cnt[i] = 0; fillc[i] = 0; }
    __syncthreads();

    int myb[CHUNK / 256];
    unsigned int myv[CHUNK / 256];
#pragma unroll
    for (int i = 0; i < CHUNK / 256; i++) {
        int off = tid + i * 256;
        if (off < n) {
            int e = e0 + off;
            int s = sp[e], d = dp[e];
            int b = d >> 7;
            myb[i] = b;
            myv[i] = ((unsigned int)(d & 127) << 16) | (unsigned int)s;
            atomicAdd(&cnt[b], 1);
        } else myb[i] = -1;
    }
    __syncthreads();

    scan[tid]       = (tid < NB) ? cnt[tid] : 0;
    scan[tid + 256] = (tid + 256 < NB) ? cnt[tid + 256] : 0;
    __syncthreads();
    for (int off = 1; off < 512; off <<= 1) {
        int a = (tid >= off) ? scan[tid - off] : 0;
        int b = (tid + 256 >= off) ? scan[tid + 256 - off] : 0;
        __syncthreads();
        scan[tid] += a; scan[tid + 256] += b;
        __syncthreads();
    }
    if (tid < NB)       lstart[tid]       = scan[tid] - cnt[tid];
    if (tid + 256 < NB) lstart[tid + 256] = scan[tid + 256] - cnt[tid + 256];
    __syncthreads();

#pragma unroll
    for (int i = 0; i < CHUNK / 256; i++) {
        int b = myb[i];
        if (b >= 0) {
            int p = lstart[b] + atomicAdd(&fillc[b], 1);
            svals[p] = myv[i];
            sbuck[p] = (short)b;
        }
    }
    if (tid < NB && cnt[tid] > 0)
        gstart[tid] = atomicAdd(&gcursor[rel * NB + tid], cnt[tid]);
    if (tid + 256 < NB && cnt[tid + 256] > 0)
        gstart[tid + 256] = atomicAdd(&gcursor[rel * NB + tid + 256], cnt[tid + 256]);
    __syncthreads();

    for (int p = tid; p < n; p += 256) {
        int b = sbuck[p];
        int pos = gstart[b] + (p - lstart[b]);
        bedges[(long long)(rel * NB + b) * BCAP + pos] = svals[p];
    }
}

// ---------------------------------------------------------------------------
// bucket_csr: per (rel,bucket) LDS counting sort -> dst-sorted src list (u16)
// + 128 local row starts.
// ---------------------------------------------------------------------------
__global__ __launch_bounds__(256) void bucket_csr_kernel(
    const unsigned int* __restrict__ bedges,
    const int* __restrict__ gcursor,
    unsigned short* __restrict__ csr16,
    int* __restrict__ browptr)
{
    __shared__ int cnt[128], sc[128], start[128], cur[128];
    __shared__ unsigned short ssorted[BCAP];

    const int id  = blockIdx.y * NB + blockIdx.x;
    const int tid = threadIdx.x;
    const int len = gcursor[id];
    const unsigned int* ep = bedges + (long long)id * BCAP;

    for (int i = tid; i < 128; i += 256) cnt[i] = 0;
    __syncthreads();
    for (int i = tid; i < len; i += 256)
        atomicAdd(&cnt[ep[i] >> 16], 1);
    __syncthreads();

    int v = (tid < 128) ? cnt[tid] : 0;
    if (tid < 128) sc[tid] = v;
    __syncthreads();
    for (int off = 1; off < 128; off <<= 1) {
        int a = (tid < 128 && tid >= off) ? sc[tid - off] : 0;
        __syncthreads();
        if (tid < 128) sc[tid] += a;
        __syncthreads();
    }
    if (tid < 128) { start[tid] = sc[tid] - v; cur[tid] = sc[tid] - v; }
    __syncthreads();

    for (int i = tid; i < len; i += 256) {
        unsigned int vv = ep[i];
        int dl = vv >> 16;
        int pos = atomicAdd(&cur[dl], 1);
        ssorted[pos] = (unsigned short)(vv & 0xFFFFu);
    }
    __syncthreads();

    for (int i = tid; i < len; i += 256)
        csr16[(long long)id * BCAP + i] = ssorted[i];
    if (tid < 128) browptr[id * 128 + tid] = start[tid];
}

// ---------------------------------------------------------------------------
// gather_csr_f16: ONE WAVE PER NODE, all 3 relations sequentially (pointer
// loads for all rels hoisted up front; 3x fewer waves; prologue amortized).
// 4x16 lane split: group g handles edges i = p0+g, p0+g+4, ...; lane l16
// loads uint2 (4 f16 = 8 B) of the source row -> one VMEM instr fetches 4
// FULL rows (512 B). Accumulation in PACKED f16 (v_pk_add_f16).
// Cross-group combine: 2 rounds of __shfl_xor on packed regs.
// ---------------------------------------------------------------------------
__global__ __launch_bounds__(256) void gather_csr_f16_kernel(
    const unsigned short* __restrict__ feat,
    const unsigned short* __restrict__ csr16,
    const int* __restrict__ browptr,
    const int* __restrict__ gcursor,
    unsigned short* __restrict__ agg,
    int M)
{
    int d = (blockIdx.x * 256 + threadIdx.x) >> 6;   // node
    int lane = threadIdx.x & 63;
    if (d >= M) return;
    int bucket = d >> 7, dl = d & 127;
    const int g = lane >> 4;                           // edge group 0..3
    const unsigned fo = (unsigned)((lane & 15) << 2);  // feature quad offset

    // hoisted row pointers for all 3 rels (6 independent loads in flight)
    int p0[RELS], p1[RELS];
#pragma unroll
    for (int r = 0; r < RELS; r++) {
        int id = r * NB + bucket;
        p0[r] = browptr[id * 128 + dl];
        p1[r] = (dl == 127) ? gcursor[id] : browptr[id * 128 + dl + 1];
    }

    unsigned short* outp = agg + (long long)d * (RELS * HID);

#pragma unroll
    for (int r = 0; r < RELS; r++) {
        const unsigned short* cp = csr16 + (long long)(r * NB + bucket) * BCAP;
        h2 aA01 = (h2)0, aA23 = (h2)0, aB01 = (h2)0, aB23 = (h2)0;
        const int e1 = p1[r];
        int i = p0[r] + g;
        for (; i + 12 < e1; i += 16) {   // 16 edges/wave per iter (4/group)
            unsigned s0 = cp[i], s1 = cp[i + 4], s2 = cp[i + 8], s3 = cp[i + 12];
            uint2 w0 = *(const uint2*)(feat + (s0 << 6) + fo);
            uint2 w1 = *(const uint2*)(feat + (s1 << 6) + fo);
            uint2 w2 = *(const uint2*)(feat + (s2 << 6) + fo);
            uint2 w3 = *(const uint2*)(feat + (s3 << 6) + fo);
            aA01 += u2h2(w0.x) + u2h2(w1.x);
            aA23 += u2h2(w0.y) + u2h2(w1.y);
            aB01 += u2h2(w2.x) + u2h2(w3.x);
            aB23 += u2h2(w2.y) + u2h2(w3.y);
        }
        if (i + 4 < e1) {                // 2 more edges for this group
            unsigned s0 = cp[i], s1 = cp[i + 4];
            uint2 w0 = *(const uint2*)(feat + (s0 << 6) + fo);
            uint2 w1 = *(const uint2*)(feat + (s1 << 6) + fo);
            aA01 += u2h2(w0.x) + u2h2(w1.x);
            aA23 += u2h2(w0.y) + u2h2(w1.y);
            i += 8;
        }
        if (i < e1) {                    // last edge for this group
            unsigned s0 = cp[i];
            uint2 w0 = *(const uint2*)(feat + (s0 << 6) + fo);
            aB01 += u2h2(w0.x);
            aB23 += u2h2(w0.y);
        }
        h2 a01 = aA01 + aB01, a23 = aA23 + aB23;

        // combine the 4 edge groups (packed): lanes l, l+16, l+32, l+48
        a01 += u2h2((unsigned)__shfl_xor((int)h2u(a01), 16));
        a23 += u2h2((unsigned)__shfl_xor((int)h2u(a23), 16));
        a01 += u2h2((unsigned)__shfl_xor((int)h2u(a01), 32));
        a23 += u2h2((unsigned)__shfl_xor((int)h2u(a23), 32));

        if (lane < 16) {
            float inv = 1.0f / fmaxf((float)(e1 - p0[r]), 1.0f);
            ushort4 o;
            o.x = f32_to_f16((float)a01.x * inv);
            o.y = f32_to_f16((float)a01.y * inv);
            o.z = f32_to_f16((float)a23.x * inv);
            o.w = f32_to_f16((float)a23.y * inv);
            *(ushort4*)(outp + r * HID + fo) = o;
        }
    }
}

// ---------------------------------------------------------------------------
// d-branch final head: out[r,s,0] = relu(z2d[r,s,:] . dW3[r] + db3[r])
// ---------------------------------------------------------------------------
__global__ void dhead_kernel(const float* __restrict__ z2d,
                             const float* __restrict__ dW3,
                             const float* __restrict__ db3,
                             float* __restrict__ out)
{
    int idx = blockIdx.x * blockDim.x + threadIdx.x;
    if (idx >= RELS * S_SEEDS) return;
    int r = idx / S_SEEDS;
    const float* zp = z2d + (long long)idx * 32;
    const float* wp = dW3 + r * 32;
    float acc = db3[r];
#pragma unroll
    for (int k = 0; k < 32; k++) acc += zp[k] * wp[k];
    out[(long long)idx * OUT_COLS] = fmaxf(acc, 0.f);
}

// ---------------------------------------------------------------------------
extern "C" void kernel_launch(void* const* d_in, const int* in_sizes, int n_in,
                              void* d_out, int out_size, void* d_ws, size_t ws_size,
                              hipStream_t stream)
{
    const float* x     = (const float*)d_in[0];
    const float* noise = (const float*)d_in[1];
    // d_in[2] = seeds: only its shape matters (S=8192); unused.
    const int* srcs[RELS] = { (const int*)d_in[3], (const int*)d_in[5], (const int*)d_in[7] };
    const int* dsts[RELS] = { (const int*)d_in[4], (const int*)d_in[6], (const int*)d_in[8] };
    const float* Wc1  = (const float*)d_in[9];
    const float* bc1  = (const float*)d_in[10];
    const float* Wc2  = (const float*)d_in[11];
    const float* bc2  = (const float*)d_in[12];
    const float* Wlin = (const float*)d_in[13];
    const float* blin = (const float*)d_in[14];
    const float* dW1  = (const float*)d_in[15];
    const float* db1  = (const float*)d_in[16];
    const float* dW2  = (const float*)d_in[17];
    const float* db2  = (const float*)d_in[18];
    const float* dW3  = (const float*)d_in[19];
    const float* db3  = (const float*)d_in[20];
    const float* fW1  = (const float*)d_in[21];
    const float* fb1  = (const float*)d_in[22];
    const float* fW2  = (const float*)d_in[23];
    const float* fb2  = (const float*)d_in[24];
    const float* fW3  = (const float*)d_in[25];
    const float* fb3  = (const float*)d_in[26];
    float* out = (float*)d_out;
    float* w   = (float*)d_ws;

    // ---- workspace layout (4-byte units; all 16B-aligned) ----
    int* gcursor = (int*)w;                                     // 1,280
    int* browptr = (int*)(w + 1280);                            // 150,144
    unsigned short* csr16 = (unsigned short*)(w + 151424);      // 1,501,440 f
    unsigned short* aggx_hf = (unsigned short*)(w + 1652864);   // REGION_A
    unsigned int*   bedges  = (unsigned int*)(w + 1652864 + 2400000);
    float*          z2d     = w + 1652864 + 2400000;
    unsigned short* xhf  = (unsigned short*)(w + 14235776);     // REGION_B
    unsigned short* z1hf = (unsigned short*)(w + 14235776);
    unsigned short* h1hf   = (unsigned short*)(w + 17381504);
    unsigned short* agg2hf = (unsigned short*)(w + 18981504);
    unsigned short* h2shf  = (unsigned short*)(w + 19767936);
    unsigned short* hshf   = (unsigned short*)(w + 20030080);
    unsigned short* WcT1   = (unsigned short*)(w + 20292224);
    unsigned short* WcT2   = (unsigned short*)(w + 20298368);
    unsigned short* WlinT  = (unsigned short*)(w + 20304512);
    unsigned short* dW1ht  = (unsigned short*)(w + 20306560);
    unsigned short* dW2ht  = (unsigned short*)(w + 20331136);
    unsigned short* fW1ht  = (unsigned short*)(w + 20343424);
    unsigned short* fW2ht  = (unsigned short*)(w + 20368000);
    unsigned short* fW3ht  = (unsigned short*)(w + 21154432);

    // ---- edge binning + per-bucket CSR ----
    hipMemsetAsync(gcursor, 0, (size_t)RELS * NB * sizeof(int), stream);
    bin_fill_kernel<<<dim3(NCHUNK, RELS), 256, 0, stream>>>(
        srcs[0], dsts[0], srcs[1], dsts[1], srcs[2], dsts[2], gcursor, bedges);
    bucket_csr_kernel<<<dim3(NB, RELS), 256, 0, stream>>>(
        bedges, gcursor, csr16, browptr);

    // ---- prep: x -> f16; all 8 weight transposes in one launch ----
    cvt_f32_f16_kernel<<<(N_NODES * HID + 255) / 256, 256, 0, stream>>>(x, xhf, (long long)N_NODES * HID);
    {
        TDs ds;
        int b0 = 0;
        auto add = [&](int k, const float* s, unsigned short* d, int K, int N, int rels) {
            ds.v[k].s = s; ds.v[k].d = d; ds.v[k].K = K; ds.v[k].N = N;
            ds.v[k].nbx = (N + 31) / 32; ds.v[k].nby = (K + 31) / 32; ds.v[k].b0 = b0;
            b0 += ds.v[k].nbx * ds.v[k].nby * rels;
        };
        add(0, Wc1, WcT1, 192, 64, 1);
        add(1, Wc2, WcT2, 192, 64, 1);
        add(2, Wlin, WlinT, 64, 64, 1);
        add(3, dW1, dW1ht, 64, 256, RELS);
        add(4, dW2, dW2ht, 256, 32, RELS);
        add(5, fW1, fW1ht, 64, 256, RELS);
        add(6, fW2, fW2ht, 256, 2048, RELS);
        add(7, fW3, fW3ht, 2048, 320, RELS);
        transpose_all_kernel<<<b0, 256, 0, stream>>>(ds);
    }

    // ---- conv layer 1: CSR gather x -> aggx (50000x192), MFMA -> h1hf ----
    gather_csr_f16_kernel<<<(N_NODES + 3) / 4, 256, 0, stream>>>(
        xhf, csr16, browptr, gcursor, aggx_hf, N_NODES);
    gemm_mfma_f16<1, true, 64, 64><<<dim3(1, (N_NODES + 63) / 64, 1), 256, 0, stream>>>(
        aggx_hf, 0, RELS * HID, WcT1, 0, bc1, 0,
        h1hf, 0, HID, nullptr, N_NODES, HID, RELS * HID);

    // ---- conv layer 2 (rows < S only), MFMA -> h2shf ----
    gather_csr_f16_kernel<<<(S_SEEDS + 3) / 4, 256, 0, stream>>>(
        h1hf, csr16, browptr, gcursor, agg2hf, S_SEEDS);
    gemm_mfma_f16<1, true, 64, 64><<<dim3(1, S_SEEDS / 64, 1), 256, 0, stream>>>(
        agg2hf, 0, RELS * HID, WcT2, 0, bc2, 0,
        h2shf, 0, HID, nullptr, S_SEEDS, HID, RELS * HID);

    // ---- hs = leaky(h2s @ Wlin + blin) + noise[:S] ----
    gemm_mfma_f16<2, true, 64, 64><<<dim3(1, S_SEEDS / 64, 1), 256, 0, stream>>>(
        h2shf, 0, HID, WlinT, 0, blin, 0,
        hshf, 0, HID, noise, S_SEEDS, HID, HID);

    // ---- d-branch: z1 -> z2d -> dhead ----
    gemm_mfma_f16<2, true, 128><<<dim3(2, S_SEEDS / 128, RELS), 256, 0, stream>>>(
        hshf, 0, HID, dW1ht, 256LL * 64, db1, 256,
        z1hf, (long long)S_SEEDS * 256, 256, nullptr, S_SEEDS, 256, HID);
    gemm_mfma_f16<2, false, 64, 64><<<dim3(1, S_SEEDS / 64, RELS), 256, 0, stream>>>(
        z1hf, (long long)S_SEEDS * 256, 256, dW2ht, 32LL * 256, db2, 32,
        z2d, (long long)S_SEEDS * 32, 32, nullptr, S_SEEDS, 32, 256);
    dhead_kernel<<<(RELS * S_SEEDS + 255) / 256, 256, 0, stream>>>(z2d, dW3, db3, out);

    // ---- f-branch: z1 = relu(hs @ fW1 + fb1), then FUSED fW2+fW3 ----
    gemm_mfma_f16<1, true, 128><<<dim3(2, S_SEEDS / 128, RELS), 256, 0, stream>>>(
        hshf, 0, HID, fW1ht, 256LL * 64, fb1, 256,
        z1hf, (long long)S_SEEDS * 256, 256, nullptr, S_SEEDS, 256, HID);
    fused_f23_kernel<<<dim3(S_SEEDS / 128, RELS), 512, 0, stream>>>(
        z1hf, fW2ht, fb2, fW3ht, fb3, out);
}